// Round 12
// baseline (95.105 us; speedup 1.0000x reference)
//
#include <hip/hip_runtime.h>

#define F 32

// ---- bucket params ----
#define TSB 128        // nodes per bucket
#define TSB_SH 7
#define NBMAX 1024     // bucket arrays padded to this (NB = ceil(N/128) <= 1024)
#define RND 4096       // edges per bin round (one block each)
#define BINT 256       // bin_kernel threads
#define GT 512         // sort_gather threads: 64 groups x 8 lanes, 2 nodes/group
#define TEDGE 2048     // entries per in-block sort tile

// ---- per-node src hist params ----
#define SPAN 8192      // nodes per histogram range (32KB LDS)
#define HBT 1024       // 16 waves/block
#define BPG 20         // blocks per range -> grid ~= 260 ~= 1/CU

// Zero scratch head with a real grid.
__global__ void zero_kernel(int4* __restrict__ p, int n4) {
    int i = blockIdx.x * blockDim.x + threadIdx.x;
    int stride = gridDim.x * blockDim.x;
    for (; i < n4; i += stride) p[i] = make_int4(0, 0, 0, 0);
}

// Fused: per-node src histogram (range grp) + per-bucket dst histogram.
__global__ __launch_bounds__(HBT) void hist2_kernel(const int* __restrict__ src,
                                                    const int* __restrict__ dst,
                                                    int* __restrict__ out_deg,
                                                    int* __restrict__ cntB,
                                                    int E, int N) {
    __shared__ int hist[SPAN];   // 32KB
    __shared__ int bh[NBMAX];    // 4KB
    int t   = threadIdx.x;
    int grp = blockIdx.x / BPG;
    int q   = blockIdx.x % BPG;
    int lo  = grp * SPAN;
    int sp  = min(SPAN, N - lo);
    bool have_range = (sp > 0);

    if (have_range)
        for (int j = t; j < SPAN; j += HBT) hist[j] = 0;
    for (int j = t; j < NBMAX; j += HBT) bh[j] = 0;
    __syncthreads();

    int nvec = E >> 2;
    const int4* d4 = (const int4*)dst;
    for (int i = blockIdx.x * HBT + t; i < nvec; i += gridDim.x * HBT) {
        int4 v = d4[i];
        atomicAdd(&bh[v.x >> TSB_SH], 1);
        atomicAdd(&bh[v.y >> TSB_SH], 1);
        atomicAdd(&bh[v.z >> TSB_SH], 1);
        atomicAdd(&bh[v.w >> TSB_SH], 1);
    }
    if (blockIdx.x == 0) {
        int idx = (nvec << 2) + t;
        if (idx < E) atomicAdd(&bh[dst[idx] >> TSB_SH], 1);
    }
    if (have_range) {
        const int4* s4 = (const int4*)src;
        for (int i = q * HBT + t; i < nvec; i += BPG * HBT) {
            int4 v = s4[i];
            unsigned a;
            a = (unsigned)(v.x - lo); if (a < (unsigned)sp) atomicAdd(&hist[a], 1);
            a = (unsigned)(v.y - lo); if (a < (unsigned)sp) atomicAdd(&hist[a], 1);
            a = (unsigned)(v.z - lo); if (a < (unsigned)sp) atomicAdd(&hist[a], 1);
            a = (unsigned)(v.w - lo); if (a < (unsigned)sp) atomicAdd(&hist[a], 1);
        }
        if (q == 0) {
            int idx = (nvec << 2) + t;
            if (idx < E) {
                unsigned a = (unsigned)(src[idx] - lo);
                if (a < (unsigned)sp) atomicAdd(&hist[a], 1);
            }
        }
    }
    __syncthreads();
    for (int j = t; j < NBMAX; j += HBT) {
        int v = bh[j];
        if (v) atomicAdd(&cntB[j], v);
    }
    if (have_range)
        for (int j = t; j < sp; j += HBT) {
            int v = hist[j];
            if (v) atomicAdd(&out_deg[lo + j], v);
        }
}

// Fused: norm (out_deg -> rsqrt, in place) + per-bucket region alloc.
__global__ void norm_alloc_kernel(int* __restrict__ deg_norm,
                                  const int* __restrict__ cntB,
                                  int* __restrict__ gcur, int* __restrict__ bases,
                                  int* __restrict__ counter, int N, int NB) {
    int i = blockIdx.x * blockDim.x + threadIdx.x;
    if (i < N) {
        int d = deg_norm[i];
        ((float*)deg_norm)[i] = rsqrtf((float)(d > 1 ? d : 1));
    }
    if (i < NB) {
        int base = atomicAdd(counter, cntB[i]);
        bases[i] = base;
        gcur[i]  = base;
    }
}

// Bin 4096 edges/block into buckets (validated R6-R11, unchanged).
__global__ __launch_bounds__(BINT) void bin_kernel(const int* __restrict__ src,
                                                   const int* __restrict__ dst,
                                                   int* __restrict__ gcur,
                                                   unsigned* __restrict__ gbuf, int E) {
    __shared__ int cnt[NBMAX];
    __shared__ int off2[NBMAX];
    __shared__ int aux[BINT];
    __shared__ int stag_d[RND];
    __shared__ int stag_s[RND];
    int t = threadIdx.x;
    int base = blockIdx.x * RND;
    int tot = min(RND, E - base);
    if (tot <= 0) return;
    for (int j = t; j < NBMAX; j += BINT) cnt[j] = 0;
    __syncthreads();
    for (int j = t; j < tot; j += BINT)
        atomicAdd(&cnt[dst[base + j] >> TSB_SH], 1);
    __syncthreads();
    int c0 = cnt[4*t], c1 = cnt[4*t+1], c2 = cnt[4*t+2], c3 = cnt[4*t+3];
    aux[t] = c0 + c1 + c2 + c3;
    __syncthreads();
    for (int o = 1; o < BINT; o <<= 1) {
        int v = (t >= o) ? aux[t - o] : 0;
        __syncthreads();
        aux[t] += v;
        __syncthreads();
    }
    int eb = t ? aux[t - 1] : 0;
    cnt[4*t]   = eb;                off2[4*t]   = eb;
    cnt[4*t+1] = eb + c0;           off2[4*t+1] = eb + c0;
    cnt[4*t+2] = eb + c0 + c1;      off2[4*t+2] = eb + c0 + c1;
    cnt[4*t+3] = eb + c0 + c1 + c2; off2[4*t+3] = eb + c0 + c1 + c2;
    __syncthreads();
    for (int j = t; j < tot; j += BINT) {
        int d = dst[base + j];
        int s = src[base + j];
        int pos = atomicAdd(&cnt[d >> TSB_SH], 1);
        stag_d[pos] = d;
        stag_s[pos] = s;
    }
    __syncthreads();
    for (int b = t; b < NBMAX; b += BINT) {
        int c = cnt[b] - off2[b];
        if (c > 0) {
            int g = atomicAdd(&gcur[b], c);
            off2[b] = g - off2[b];
        }
    }
    __syncthreads();
    for (int i = t; i < tot; i += BINT) {
        int d = stag_d[i];
        unsigned entry = ((unsigned)(d & (TSB - 1)) << 17) | (unsigned)stag_s[i];
        gbuf[off2[d >> TSB_SH] + i] = entry;
    }
}

// Phase 2: counting sort + REGISTER accumulation with batched-8 consume.
// Entries staged in registers (single gbuf read). Group ga owns nodes ga, ga+64.
__global__ __launch_bounds__(GT) void sort_gather(const float* __restrict__ x,
                                                  const float* __restrict__ onorm,
                                                  const unsigned* __restrict__ gbuf,
                                                  const int* __restrict__ bases,
                                                  const int* __restrict__ cntB,
                                                  float* __restrict__ out, int N) {
    __shared__ unsigned sbuf[TEDGE];  // 8KB
    __shared__ int cnt[TSB];
    __shared__ int seg[TSB];
    __shared__ int indeg[TSB];
    int t = threadIdx.x;
    int b = blockIdx.x;
    int lo = b << TSB_SH;
    int sp = min(TSB, N - lo);
    int start = bases[b];
    int total = cntB[b];
    int ga = t >> 3;
    int l  = t & 7;
    const float4* x4 = (const float4*)x;

    float4 acc0 = make_float4(0.f, 0.f, 0.f, 0.f);
    float4 acc1 = make_float4(0.f, 0.f, 0.f, 0.f);
    if (t < TSB) indeg[t] = 0;
    __syncthreads();

    for (int tile = 0; tile < total; tile += TEDGE) {
        int n = min(TEDGE, total - tile);
        // stage this thread's entries into registers (single global read)
        unsigned ev[TEDGE / GT];  // 4
        int nm = 0;
        #pragma unroll
        for (int k = 0; k < TEDGE / GT; ++k) {
            int j = t + k * GT;
            if (j < n) { ev[k] = gbuf[start + tile + j]; nm = k + 1; }
        }
        if (t < TSB) cnt[t] = 0;
        __syncthreads();
        // count from regs
        #pragma unroll
        for (int k = 0; k < TEDGE / GT; ++k)
            if (k < nm) atomicAdd(&cnt[ev[k] >> 17], 1);
        __syncthreads();
        if (t < TSB) indeg[t] += cnt[t];
        __syncthreads();
        // wave-0 shfl scan of cnt[128]
        if (t < 64) {
            int c0 = cnt[2 * t], c1 = cnt[2 * t + 1];
            int p = c0 + c1;
            #pragma unroll
            for (int o = 1; o < 64; o <<= 1) {
                int v = __shfl_up(p, o, 64);
                if (t >= o) p += v;
            }
            int excl = p - (c0 + c1);
            seg[2 * t] = excl;          cnt[2 * t] = excl;
            seg[2 * t + 1] = excl + c0; cnt[2 * t + 1] = excl + c0;
        }
        __syncthreads();
        // place from regs
        #pragma unroll
        for (int k = 0; k < TEDGE / GT; ++k)
            if (k < nm) {
                unsigned e = ev[k];
                int pos = atomicAdd(&cnt[e >> 17], 1);
                sbuf[pos] = e;
            }
        __syncthreads();
        // consume: batched-8 register accumulation (8 independent x loads in flight)
        #pragma unroll
        for (int half = 0; half < 2; ++half) {
            int g = ga + half * 64;
            float4 a = half ? acc1 : acc0;
            int i = seg[g];
            int send = cnt[g];
            for (; i + 8 <= send; i += 8) {
                unsigned es[8]; float cs[8]; float4 vs[8];
                #pragma unroll
                for (int k = 0; k < 8; ++k) es[k] = sbuf[i + k] & 0x1FFFFu;
                #pragma unroll
                for (int k = 0; k < 8; ++k) cs[k] = onorm[es[k]];
                #pragma unroll
                for (int k = 0; k < 8; ++k) vs[k] = x4[(size_t)es[k] * 8 + l];
                #pragma unroll
                for (int k = 0; k < 8; ++k) {
                    a.x += vs[k].x * cs[k];
                    a.y += vs[k].y * cs[k];
                    a.z += vs[k].z * cs[k];
                    a.w += vs[k].w * cs[k];
                }
            }
            // tail (<8)
            if (i < send) {
                unsigned es[8]; float cs[8]; float4 vs[8];
                int m = send - i;
                #pragma unroll
                for (int k = 0; k < 8; ++k) es[k] = sbuf[i + (k < m ? k : 0)] & 0x1FFFFu;
                #pragma unroll
                for (int k = 0; k < 8; ++k) cs[k] = onorm[es[k]];
                #pragma unroll
                for (int k = 0; k < 8; ++k) vs[k] = x4[(size_t)es[k] * 8 + l];
                #pragma unroll
                for (int k = 0; k < 8; ++k) {
                    if (k < m) {
                        a.x += vs[k].x * cs[k];
                        a.y += vs[k].y * cs[k];
                        a.z += vs[k].z * cs[k];
                        a.w += vs[k].w * cs[k];
                    }
                }
            }
            if (half) acc1 = a; else acc0 = a;
        }
        __syncthreads();
    }

    #pragma unroll
    for (int half = 0; half < 2; ++half) {
        int g = ga + half * 64;
        if (g < sp) {
            float4 a = half ? acc1 : acc0;
            int dg = indeg[g];
            float inn = rsqrtf((float)(dg > 1 ? dg : 1));
            a.x *= inn; a.y *= inn; a.z *= inn; a.w *= inn;
            *reinterpret_cast<float4*>(&out[(size_t)(lo + g) * F + l * 4]) = a;
        }
    }
}

// ================= R3 fallback path =================

__global__ void deg_kernel(const int* __restrict__ src, const int* __restrict__ dst,
                           int* __restrict__ out_deg, int* __restrict__ in_deg, int E) {
    int i = blockIdx.x * blockDim.x + threadIdx.x;
    if (i < E) {
        atomicAdd(&out_deg[src[i]], 1);
        atomicAdd(&in_deg[dst[i]], 1);
    }
}

__global__ void norm_kernel(const int* __restrict__ deg, float* __restrict__ norm, int n) {
    int i = blockIdx.x * blockDim.x + threadIdx.x;
    if (i < n) {
        int d = deg[i];
        norm[i] = rsqrtf((float)(d > 1 ? d : 1));
    }
}

__global__ void alloc_kernel(const int* __restrict__ in_deg, int* __restrict__ cursor,
                             int* __restrict__ counter, int N) {
    int i = blockIdx.x * blockDim.x + threadIdx.x;
    if (i < N) cursor[i] = atomicAdd(counter, in_deg[i]);
}

__global__ void fill_kernel(const int* __restrict__ src, const int* __restrict__ dst,
                            int* __restrict__ cursor, int* __restrict__ edge_src, int E) {
    int i = blockIdx.x * blockDim.x + threadIdx.x;
    if (i < E) {
        int d = dst[i];
        int slot = atomicAdd(&cursor[d], 1);
        edge_src[slot] = src[i];
    }
}

__global__ void gather_kernel(const float* __restrict__ x,
                              const int* __restrict__ edge_src,
                              const int* __restrict__ cursor_end,
                              const int* __restrict__ in_deg,
                              const float* __restrict__ out_norm,
                              float* __restrict__ out, int N) {
    int t = blockIdx.x * blockDim.x + threadIdx.x;
    int g = t >> 3, l = t & 7;
    if (g >= N) return;
    int deg = in_deg[g];
    int end = cursor_end[g];
    int beg = end - deg;
    float4 acc = make_float4(0.f, 0.f, 0.f, 0.f);
    for (int j = beg; j < end; ++j) {
        int s = edge_src[j];
        float c = out_norm[s];
        float4 v = *reinterpret_cast<const float4*>(&x[s * F + l * 4]);
        acc.x += v.x * c; acc.y += v.y * c; acc.z += v.z * c; acc.w += v.w * c;
    }
    float innorm = rsqrtf((float)(deg > 1 ? deg : 1));
    acc.x *= innorm; acc.y *= innorm; acc.z *= innorm; acc.w *= innorm;
    *reinterpret_cast<float4*>(&out[g * F + l * 4]) = acc;
}

extern "C" void kernel_launch(void* const* d_in, const int* in_sizes, int n_in,
                              void* d_out, int out_size, void* d_ws, size_t ws_size,
                              hipStream_t stream) {
    const float* x  = (const float*)d_in[0];
    const int* src  = (const int*)d_in[1];
    const int* dst  = (const int*)d_in[2];
    float* out      = (float*)d_out;

    const int N = in_sizes[0] / F;   // 100000
    const int E = in_sizes[1];       // 1600000
    const int NB = (N + TSB - 1) / TSB;

    size_t need = ((size_t)N + 8 + 3 * NBMAX + (size_t)E) * 4;

    if (ws_size >= need && N <= (1 << 17) && NB <= NBMAX) {
        int* out_deg  = (int*)d_ws;
        int* counter  = out_deg + N;
        int* cntB     = counter + 8;
        int* gcur     = cntB + NBMAX;
        int* bases    = gcur + NBMAX;
        unsigned* gbuf = (unsigned*)(bases + NBMAX);

        int zn4 = (int)(((size_t)N + 8 + NBMAX) / 4);
        zero_kernel<<<128, 256, 0, stream>>>((int4*)d_ws, zn4);

        int G = (N + SPAN - 1) / SPAN;
        hist2_kernel<<<G * BPG, HBT, 0, stream>>>(src, dst, out_deg, cntB, E, N);
        norm_alloc_kernel<<<(N + 255) / 256, 256, 0, stream>>>(
            out_deg, cntB, gcur, bases, counter, N, NB);
        bin_kernel<<<(E + RND - 1) / RND, BINT, 0, stream>>>(src, dst, gcur, gbuf, E);
        sort_gather<<<NB, GT, 0, stream>>>(x, (const float*)out_deg, gbuf, bases,
                                           cntB, out, N);
        return;
    }

    // ---- R3 fallback ----
    size_t need3 = ((size_t)3 * N + 1 + (size_t)E) * sizeof(int);
    int* out_deg = (int*)d_ws;
    int* in_deg  = out_deg + N;
    if (ws_size >= need3) {
        int* counter  = in_deg + N;
        int* cursor   = counter + 1;
        int* edge_src = cursor + N;
        hipMemsetAsync(d_ws, 0, ((size_t)2 * N + 1) * sizeof(int), stream);
        deg_kernel<<<(E + 255) / 256, 256, 0, stream>>>(src, dst, out_deg, in_deg, E);
        norm_kernel<<<(N + 255) / 256, 256, 0, stream>>>(out_deg, (float*)out_deg, N);
        alloc_kernel<<<(N + 255) / 256, 256, 0, stream>>>(in_deg, cursor, counter, N);
        fill_kernel<<<(E + 255) / 256, 256, 0, stream>>>(src, dst, cursor, edge_src, E);
        gather_kernel<<<(N * 8 + 255) / 256, 256, 0, stream>>>(
            x, edge_src, cursor, in_deg, (const float*)out_deg, out, N);
    }
}